// Round 13
// baseline (226.816 us; speedup 1.0000x reference)
//
#include <hip/hip_runtime.h>
#include <math.h>

#define NEG_SLOPE_F 0.2f
#define NB    512     // dst buckets
#define NBLK  256     // binning chunk blocks
#define OSCAP 6912    // binA LDS sort cap >= chunk
#define BCAP  4096    // aggB per-bucket LDS edge cap (mean ~3330, +13 sigma)

typedef __attribute__((ext_vector_type(8)))  short short8;
typedef __attribute__((ext_vector_type(16))) float f32x16;

static __device__ __forceinline__ float lrelu(float x) {
    return x > 0.f ? x : NEG_SLOPE_F * x;
}
static __device__ __forceinline__ unsigned f2bf(float f) {
    unsigned u = __float_as_uint(f);
    return (u + 0x7FFFu + ((u >> 16) & 1u)) >> 16;
}
static __device__ __forceinline__ float bflo(unsigned w) { return __uint_as_float(w << 16); }
static __device__ __forceinline__ float bfhi(unsigned w) { return __uint_as_float(w & 0xFFFF0000u); }

static __device__ __forceinline__ int bucket_of(int d, int nps, float inv_nps) {
    int b = (int)((float)d * inv_nps);
    if (d < b * nps) --b;
    else if (d >= (b + 1) * nps) ++b;
    return b;
}

// ---------------- countA (+Wt init in first 64 blocks) ----------------
// Per chunk-block: LDS hist over 512 buckets + pairwise in-block scan.
__global__ __launch_bounds__(256) void k_countA(const float* __restrict__ W, unsigned short* __restrict__ Wt,
                                                const int* __restrict__ ei, int E, int N,
                                                int nps, float inv_nps,
                                                int* __restrict__ cntT, int* __restrict__ fragRow,
                                                int* __restrict__ rowTot, int chunk) {
    __shared__ int hist[NB];
    __shared__ int sm[256];
    int bid = blockIdx.x, tid = threadIdx.x;
    if (bid < 64) {
        int g = bid * 256 + tid;
        int c = g >> 7, k = g & 127;
        Wt[c * 128 + k] = (unsigned short)f2bf(W[k * 128 + c]);
    }
    hist[tid] = 0; hist[tid + 256] = 0;
    __syncthreads();
    int total = E + N;
    int lo = bid * chunk;
    int hi = lo + chunk; if (hi > total) hi = total;
    for (int t = lo + tid; t < hi; t += 256) {
        int s, d;
        if (t < E) { s = ei[t]; d = ei[E + t]; }
        else       { s = t - E; d = s; }
        if ((unsigned)s >= (unsigned)N || (unsigned)d >= (unsigned)N) continue;
        atomicAdd(&hist[bucket_of(d, nps, inv_nps)], 1);
    }
    __syncthreads();
    int e0 = hist[2 * tid], e1 = hist[2 * tid + 1];
    int ps = e0 + e1;
    sm[tid] = ps; __syncthreads();
    int acc = ps;
    for (int off = 1; off < 256; off <<= 1) {
        int o = (tid >= (unsigned)off) ? sm[tid - off] : 0;
        __syncthreads();
        acc += o; sm[tid] = acc; __syncthreads();
    }
    int excl = acc - ps;
    fragRow[bid * NB + 2 * tid]     = excl;
    fragRow[bid * NB + 2 * tid + 1] = excl + e0;
    cntT[(2 * tid) * NBLK + bid]     = e0;
    cntT[(2 * tid + 1) * NBLK + bid] = e1;
    if (tid == 255) rowTot[bid] = acc;
}

// ---------------- fused: scanR (block 0) + MFMA GEMM (blocks 1..) ----------
__global__ __launch_bounds__(256) void k_gemm_scanR(
        const float* __restrict__ x, const unsigned short* __restrict__ Wt,
        unsigned short* __restrict__ h, int M,
        const int* __restrict__ rowTot, int* __restrict__ frag) {
    int bid = (int)blockIdx.x;
    int tid = threadIdx.x;

    if (bid == 0) {
        // ---- scanR: block bases + frag fixup (no bucketBase needed anymore)
        __shared__ int sm[256];
        __shared__ int blockBase[NBLK];
        int v = rowTot[tid];
        sm[tid] = v; __syncthreads();
        int acc = v;
        for (int off = 1; off < 256; off <<= 1) {
            int o = (tid >= (unsigned)off) ? sm[tid - off] : 0;
            __syncthreads();
            acc += o; sm[tid] = acc; __syncthreads();
        }
        blockBase[tid] = acc - v;
        __syncthreads();
        for (int p = tid; p < NBLK * NB; p += 256)
            frag[p] += blockBase[p >> 9];          // NB=512 -> row = p>>9
        return;
    }

    // ---- MFMA GEMM: 128x128 per block, 4 waves x 32 rows ----
    int w = tid >> 6;
    int lane = tid & 63;
    int l31 = lane & 31;
    int lh = lane >> 5;
    int row0 = (bid - 1) * 128 + w * 32;

    f32x16 acc0, acc1, acc2, acc3;
#pragma unroll
    for (int i = 0; i < 16; ++i) { acc0[i] = 0.f; acc1[i] = 0.f; acc2[i] = 0.f; acc3[i] = 0.f; }

    int arow = row0 + l31;
    if (arow >= M) arow = M - 1;

    for (int k0 = 0; k0 < 128; k0 += 16) {
        int kb = k0 + lh * 8;
        float4 v0 = *(const float4*)&x[(size_t)arow * 128 + kb];
        float4 v1 = *(const float4*)&x[(size_t)arow * 128 + kb + 4];
        short8 a;
        a[0] = (short)f2bf(v0.x); a[1] = (short)f2bf(v0.y);
        a[2] = (short)f2bf(v0.z); a[3] = (short)f2bf(v0.w);
        a[4] = (short)f2bf(v1.x); a[5] = (short)f2bf(v1.y);
        a[6] = (short)f2bf(v1.z); a[7] = (short)f2bf(v1.w);
        short8 b0 = *(const short8*)&Wt[(0 * 32 + l31) * 128 + kb];
        short8 b1 = *(const short8*)&Wt[(1 * 32 + l31) * 128 + kb];
        short8 b2 = *(const short8*)&Wt[(2 * 32 + l31) * 128 + kb];
        short8 b3 = *(const short8*)&Wt[(3 * 32 + l31) * 128 + kb];
        acc0 = __builtin_amdgcn_mfma_f32_32x32x16_bf16(a, b0, acc0, 0, 0, 0);
        acc1 = __builtin_amdgcn_mfma_f32_32x32x16_bf16(a, b1, acc1, 0, 0, 0);
        acc2 = __builtin_amdgcn_mfma_f32_32x32x16_bf16(a, b2, acc2, 0, 0, 0);
        acc3 = __builtin_amdgcn_mfma_f32_32x32x16_bf16(a, b3, acc3, 0, 0, 0);
    }
#pragma unroll
    for (int reg = 0; reg < 16; ++reg) {
        int row = row0 + (reg & 3) + 8 * (reg >> 2) + 4 * lh;
        if (row < M) {
            size_t rb = (size_t)row * 128;
            h[rb +  0 + l31] = (unsigned short)f2bf(acc0[reg]);
            h[rb + 32 + l31] = (unsigned short)f2bf(acc1[reg]);
            h[rb + 64 + l31] = (unsigned short)f2bf(acc2[reg]);
            h[rb + 96 + l31] = (unsigned short)f2bf(acc3[reg]);
        }
    }
}

// ---------------- fused: binA (LDS counting-sort) + att ----------------
__global__ __launch_bounds__(256) void k_binA_att(
        const int* __restrict__ ei, int E, int N, int nps, float inv_nps,
        const int* __restrict__ frag, unsigned* __restrict__ pairs, int chunk,
        const unsigned short* __restrict__ h,
        const float* __restrict__ att_s, const float* __restrict__ att_d,
        float* __restrict__ as, float* __restrict__ ad) {
    __shared__ int cur[NB];
    __shared__ unsigned osort[OSCAP];
    int bid = (int)blockIdx.x;
    int tid = threadIdx.x;

    if (bid < NBLK) {
        int base0 = frag[bid * NB];
        cur[tid]       = frag[bid * NB + tid] - base0;
        cur[tid + 256] = frag[bid * NB + tid + 256] - base0;
        __syncthreads();
        int total = E + N;
        int lo = bid * chunk;
        int hi = lo + chunk; if (hi > total) hi = total;
        for (int t = lo + tid; t < hi; t += 256) {
            int s, d;
            if (t < E) { s = ei[t]; d = ei[E + t]; }
            else       { s = t - E; d = s; }
            if ((unsigned)s >= (unsigned)N || (unsigned)d >= (unsigned)N) continue;
            int b = bucket_of(d, nps, inv_nps);
            int pos = atomicAdd(&cur[b], 1);
            osort[pos] = ((unsigned)s << 9) | (unsigned)(d - b * nps);
        }
        __syncthreads();
        int m = cur[NB - 1];
        for (int j = tid; j < m; j += 256)
            pairs[base0 + j] = osort[j];
        return;
    }

    // ---- att role ----
    int g = (bid - NBLK) * 256 + tid;
    int n = g >> 6;
    int j = g & 63;
    if (n >= N) return;
    unsigned u = ((const unsigned*)h)[(size_t)n * 64 + j];
    float lo = bflo(u), hi = bfhi(u);
    float ps = lo * att_s[2 * j] + hi * att_s[2 * j + 1];
    float pd = lo * att_d[2 * j] + hi * att_d[2 * j + 1];
#pragma unroll
    for (int off = 8; off >= 1; off >>= 1) {
        ps += __shfl_xor(ps, off, 64);
        pd += __shfl_xor(pd, off, 64);
    }
    if ((j & 15) == 0) {
        int hh = j >> 4;
        as[n * 4 + hh] = ps;
        ad[n * 4 + hh] = pd;
    }
}

// ---------------- aggB: LDS CSR build + aggregate (one block per bucket) ----
__global__ __launch_bounds__(1024) void k_aggB(
        const unsigned short* __restrict__ h, const unsigned* __restrict__ pairs,
        const int* __restrict__ cntT, const int* __restrict__ frag,
        const float* __restrict__ as, const float* __restrict__ ad,
        const float* __restrict__ bias,
        float* __restrict__ out, int N, int nps) {
    __shared__ unsigned edges[BCAP];
    __shared__ int csrcL[BCAP];
    __shared__ int foff[NBLK];
    __shared__ int fcs[NBLK];
    __shared__ int flof[NBLK + 1];
    __shared__ int hist[NB];
    __shared__ int rpt[NB + 1];
    __shared__ int cur[NB];
    __shared__ int sm[1024];

    int b = blockIdx.x;
    int tid = threadIdx.x;
    int dlo = b * nps;
    if (dlo >= N) return;
    int npsb = nps; if (dlo + npsb > N) npsb = N - dlo;

    if (tid < NBLK) { foff[tid] = frag[tid * NB + b]; fcs[tid] = cntT[b * NBLK + tid]; }
    if (tid < NB) hist[tid] = 0;
    __syncthreads();

    // scan fragment counts -> flof
    int v = (tid < NBLK) ? fcs[tid] : 0;
    sm[tid] = v; __syncthreads();
    int acc = v;
    for (int off = 1; off < 1024; off <<= 1) {
        int o = (tid >= (unsigned)off) ? sm[tid - off] : 0;
        __syncthreads();
        acc += o; sm[tid] = acc; __syncthreads();
    }
    if (tid < NBLK) flof[tid] = acc - v;
    if (tid == NBLK - 1) flof[NBLK] = acc;
    __syncthreads();
    int m = flof[NBLK]; if (m > BCAP) m = BCAP;

    // copy fragments into LDS (fragment-owner threads; runs are contiguous)
    if (tid < NBLK) {
        int fo = foff[tid], st = flof[tid], fc = fcs[tid];
        for (int j = 0; j < fc; ++j) {
            int p = st + j;
            if (p < BCAP) edges[p] = pairs[fo + j];
        }
    }
    __syncthreads();

    // histogram by dst-local
    for (int e = tid; e < m; e += 1024)
        atomicAdd(&hist[edges[e] & 511], 1);
    __syncthreads();

    // scan hist -> rpt, cursors
    int hv = (tid < NB) ? hist[tid] : 0;
    sm[tid] = hv; __syncthreads();
    int acc2 = hv;
    for (int off = 1; off < 1024; off <<= 1) {
        int o = (tid >= (unsigned)off) ? sm[tid - off] : 0;
        __syncthreads();
        acc2 += o; sm[tid] = acc2; __syncthreads();
    }
    if (tid < NB) { rpt[tid] = acc2 - hv; cur[tid] = acc2 - hv; }
    if (tid == NB - 1) rpt[NB] = acc2;
    __syncthreads();

    // scatter srcs into csrcL
    for (int e = tid; e < m; e += 1024) {
        unsigned pk = edges[e];
        int pos = atomicAdd(&cur[pk & 511], 1);
        csrcL[pos] = (int)(pk >> 9);
    }
    __syncthreads();

    // aggregate: wave per node, 4 edges in flight (quarter-wave uint4)
    int wv = tid >> 6;
    int lane = tid & 63;
    int qt = lane >> 4;
    int q  = lane & 15;
    int head = q >> 2;
    const uint4* hp = (const uint4*)h;

    for (int dl = wv; dl < npsb; dl += 16) {
        int n = dlo + dl;
        int o0 = rpt[dl];
        int deg = rpt[dl + 1] - o0;
        float adh = ad[(size_t)n * 4 + head];

        float a0 = 0.f, a1 = 0.f, a2 = 0.f, a3 = 0.f;
        float a4 = 0.f, a5 = 0.f, a6 = 0.f, a7 = 0.f, sw = 0.f;
        for (int i = qt; i < deg; i += 4) {
            int s = csrcL[o0 + i];
            float e = lrelu(as[(size_t)s * 4 + head] + adh);
            float w = __expf(e);
            uint4 u = hp[(size_t)s * 16 + q];
            a0 = fmaf(w, bflo(u.x), a0); a1 = fmaf(w, bfhi(u.x), a1);
            a2 = fmaf(w, bflo(u.y), a2); a3 = fmaf(w, bfhi(u.y), a3);
            a4 = fmaf(w, bflo(u.z), a4); a5 = fmaf(w, bfhi(u.z), a5);
            a6 = fmaf(w, bflo(u.w), a6); a7 = fmaf(w, bfhi(u.w), a7);
            sw += w;
        }
        a0 += __shfl_xor(a0, 16, 64); a0 += __shfl_xor(a0, 32, 64);
        a1 += __shfl_xor(a1, 16, 64); a1 += __shfl_xor(a1, 32, 64);
        a2 += __shfl_xor(a2, 16, 64); a2 += __shfl_xor(a2, 32, 64);
        a3 += __shfl_xor(a3, 16, 64); a3 += __shfl_xor(a3, 32, 64);
        a4 += __shfl_xor(a4, 16, 64); a4 += __shfl_xor(a4, 32, 64);
        a5 += __shfl_xor(a5, 16, 64); a5 += __shfl_xor(a5, 32, 64);
        a6 += __shfl_xor(a6, 16, 64); a6 += __shfl_xor(a6, 32, 64);
        a7 += __shfl_xor(a7, 16, 64); a7 += __shfl_xor(a7, 32, 64);
        sw += __shfl_xor(sw, 16, 64); sw += __shfl_xor(sw, 32, 64);

        if (qt == 0) {
            float inv = 1.f / (sw + 1e-16f);
            int d0 = q * 8;
            float4 b0 = *(const float4*)&bias[d0];
            float4 b1 = *(const float4*)&bias[d0 + 4];
            float r0 = fmaf(a0, inv, b0.x);
            float r1 = fmaf(a1, inv, b0.y);
            float r2 = fmaf(a2, inv, b0.z);
            float r3 = fmaf(a3, inv, b0.w);
            float r4 = fmaf(a4, inv, b1.x);
            float r5 = fmaf(a5, inv, b1.y);
            float r6 = fmaf(a6, inv, b1.z);
            float r7 = fmaf(a7, inv, b1.w);
            r0 = r0 > 0.f ? r0 : __expf(r0) - 1.f;
            r1 = r1 > 0.f ? r1 : __expf(r1) - 1.f;
            r2 = r2 > 0.f ? r2 : __expf(r2) - 1.f;
            r3 = r3 > 0.f ? r3 : __expf(r3) - 1.f;
            r4 = r4 > 0.f ? r4 : __expf(r4) - 1.f;
            r5 = r5 > 0.f ? r5 : __expf(r5) - 1.f;
            r6 = r6 > 0.f ? r6 : __expf(r6) - 1.f;
            r7 = r7 > 0.f ? r7 : __expf(r7) - 1.f;
            *(float4*)&out[(size_t)n * 128 + d0] = make_float4(r0, r1, r2, r3);
            *(float4*)&out[(size_t)n * 128 + d0 + 4] = make_float4(r4, r5, r6, r7);
        }
    }
}

// ---------------- launch ----------------
extern "C" void kernel_launch(void* const* d_in, const int* in_sizes, int n_in,
                              void* d_out, int out_size, void* d_ws, size_t ws_size,
                              hipStream_t stream) {
    const float* x     = (const float*)d_in[0];
    const int*   ei    = (const int*)d_in[1];     // int32 [2][E] flat
    const float* W     = (const float*)d_in[2];
    const float* att_s = (const float*)d_in[3];
    const float* att_d = (const float*)d_in[4];
    const float* bias  = (const float*)d_in[5];
    float* out = (float*)d_out;

    int N = in_sizes[0] / 128;
    int E = in_sizes[1] / 2;
    int total = E + N;

    int nps = (N + NB - 1) / NB;                  // 196 (<512 for 9-bit pack)
    float inv_nps = 1.0f / (float)nps;
    int chunk = (total + NBLK - 1) / NBLK;        // ~6642 (<= OSCAP)

    auto align256 = [](size_t v) { return (v + 255) & ~(size_t)255; };
    char* wsp = (char*)d_ws;
    size_t off = 0;
    auto alloc = [&](size_t bytes) {
        char* p = wsp + off;
        off += align256(bytes);
        return p;
    };
    unsigned short* h  = (unsigned short*)alloc((size_t)N * 128 * 2);
    unsigned short* Wt = (unsigned short*)alloc(128 * 128 * 2);
    float* as        = (float*)alloc((size_t)N * 16);
    float* ad        = (float*)alloc((size_t)N * 16);
    int*   cntT      = (int*)alloc((size_t)NB * NBLK * 4);
    int*   frag      = (int*)alloc((size_t)NBLK * NB * 4);   // fragRow -> frag in-place
    int*   rowTot    = (int*)alloc((size_t)NBLK * 4);
    unsigned* pairs  = (unsigned*)alloc((size_t)total * 4);
    (void)ws_size;

    int nGemm = (N + 127) / 128;                  // 782
    int nAtt  = ((size_t)N * 64 + 255) / 256;     // 25000

    k_countA<<<NBLK, 256, 0, stream>>>(W, Wt, ei, E, N, nps, inv_nps, cntT, frag, rowTot, chunk);
    k_gemm_scanR<<<1 + nGemm, 256, 0, stream>>>(x, Wt, h, N, rowTot, frag);
    k_binA_att<<<NBLK + nAtt, 256, 0, stream>>>(ei, E, N, nps, inv_nps, frag, pairs, chunk,
                                                h, att_s, att_d, as, ad);
    k_aggB<<<NB, 1024, 0, stream>>>(h, pairs, cntT, frag, as, ad, bias, out, N, nps);
}

// Round 14
// 216.818 us; speedup vs baseline: 1.0461x; 1.0461x over previous
//
#include <hip/hip_runtime.h>
#include <math.h>

#define NEG_SLOPE_F 0.2f
#define NB    256     // dst buckets
#define NBLK  256     // binning chunk blocks
#define OSCAP 6912    // binA LDS sort cap >= chunk

typedef __attribute__((ext_vector_type(8)))  short short8;
typedef __attribute__((ext_vector_type(16))) float f32x16;

static __device__ __forceinline__ float lrelu(float x) {
    return x > 0.f ? x : NEG_SLOPE_F * x;
}
static __device__ __forceinline__ unsigned f2bf(float f) {
    unsigned u = __float_as_uint(f);
    return (u + 0x7FFFu + ((u >> 16) & 1u)) >> 16;
}
static __device__ __forceinline__ float bflo(unsigned w) { return __uint_as_float(w << 16); }
static __device__ __forceinline__ float bfhi(unsigned w) { return __uint_as_float(w & 0xFFFF0000u); }

static __device__ __forceinline__ int bucket_of(int d, int nps, float inv_nps) {
    int b = (int)((float)d * inv_nps);
    if (d < b * nps) --b;
    else if (d >= (b + 1) * nps) ++b;
    return b;
}

// ---------------- countA (+Wt init in first 64 blocks) ----------------
__global__ __launch_bounds__(256) void k_countA(const float* __restrict__ W, unsigned short* __restrict__ Wt,
                                                const int* __restrict__ ei, int E, int N,
                                                int nps, float inv_nps,
                                                int* __restrict__ cntT, int* __restrict__ fragRow,
                                                int* __restrict__ rowTot, int chunk) {
    __shared__ int hist[NB];
    __shared__ int sm[NB];
    int bid = blockIdx.x, tid = threadIdx.x;
    if (bid < 64) {
        int g = bid * 256 + tid;
        int c = g >> 7, k = g & 127;
        Wt[c * 128 + k] = (unsigned short)f2bf(W[k * 128 + c]);
    }
    hist[tid] = 0;
    __syncthreads();
    int total = E + N;
    int lo = bid * chunk;
    int hi = lo + chunk; if (hi > total) hi = total;
    for (int t = lo + tid; t < hi; t += 256) {
        int s, d;
        if (t < E) { s = ei[t]; d = ei[E + t]; }
        else       { s = t - E; d = s; }
        if ((unsigned)s >= (unsigned)N || (unsigned)d >= (unsigned)N) continue;
        atomicAdd(&hist[bucket_of(d, nps, inv_nps)], 1);
    }
    __syncthreads();
    int v = hist[tid];
    sm[tid] = v;
    __syncthreads();
    int acc = v;
    for (int off = 1; off < 256; off <<= 1) {
        int o = (tid >= (unsigned)off) ? sm[tid - off] : 0;
        __syncthreads();
        acc += o; sm[tid] = acc; __syncthreads();
    }
    fragRow[bid * NB + tid] = acc - v;             // local exclusive
    cntT[tid * NBLK + bid] = v;
    if (tid == 255) rowTot[bid] = acc;
}

// ---------------- fused: scanR+bucketBase (block 0) + MFMA GEMM ----------
__global__ __launch_bounds__(256) void k_gemm_scanR(
        const float* __restrict__ x, const unsigned short* __restrict__ Wt,
        unsigned short* __restrict__ h, int M,
        const int* __restrict__ rowTot, int* __restrict__ frag,
        const int* __restrict__ cntT, int* __restrict__ bucketBase) {
    int bid = (int)blockIdx.x;
    int tid = threadIdx.x;

    if (bid == 0) {
        __shared__ int sm[256];
        __shared__ int blockBase[NBLK];
        int v = rowTot[tid];
        sm[tid] = v; __syncthreads();
        int acc = v;
        for (int off = 1; off < 256; off <<= 1) {
            int o = (tid >= (unsigned)off) ? sm[tid - off] : 0;
            __syncthreads();
            acc += o; sm[tid] = acc; __syncthreads();
        }
        blockBase[tid] = acc - v;
        __syncthreads();
        for (int p = tid; p < NBLK * NB; p += 256)
            frag[p] += blockBase[p >> 8];          // NB=256 -> row = p>>8

        // bucket bases: thread t sums its own contiguous cntT row, then scan
        int cv = 0;
        const int* row = cntT + tid * NBLK;
        for (int i = 0; i < NBLK; ++i) cv += row[i];
        __syncthreads();
        sm[tid] = cv; __syncthreads();
        int acc2 = cv;
        for (int off = 1; off < 256; off <<= 1) {
            int o = (tid >= (unsigned)off) ? sm[tid - off] : 0;
            __syncthreads();
            acc2 += o; sm[tid] = acc2; __syncthreads();
        }
        bucketBase[tid] = acc2 - cv;
        if (tid == 255) bucketBase[NB] = acc2;
        return;
    }

    // ---- MFMA GEMM: 128x128 per block, 4 waves x 32 rows ----
    int w = tid >> 6;
    int lane = tid & 63;
    int l31 = lane & 31;
    int lh = lane >> 5;
    int row0 = (bid - 1) * 128 + w * 32;

    f32x16 acc0, acc1, acc2, acc3;
#pragma unroll
    for (int i = 0; i < 16; ++i) { acc0[i] = 0.f; acc1[i] = 0.f; acc2[i] = 0.f; acc3[i] = 0.f; }

    int arow = row0 + l31;
    if (arow >= M) arow = M - 1;

    for (int k0 = 0; k0 < 128; k0 += 16) {
        int kb = k0 + lh * 8;
        float4 v0 = *(const float4*)&x[(size_t)arow * 128 + kb];
        float4 v1 = *(const float4*)&x[(size_t)arow * 128 + kb + 4];
        short8 a;
        a[0] = (short)f2bf(v0.x); a[1] = (short)f2bf(v0.y);
        a[2] = (short)f2bf(v0.z); a[3] = (short)f2bf(v0.w);
        a[4] = (short)f2bf(v1.x); a[5] = (short)f2bf(v1.y);
        a[6] = (short)f2bf(v1.z); a[7] = (short)f2bf(v1.w);
        short8 b0 = *(const short8*)&Wt[(0 * 32 + l31) * 128 + kb];
        short8 b1 = *(const short8*)&Wt[(1 * 32 + l31) * 128 + kb];
        short8 b2 = *(const short8*)&Wt[(2 * 32 + l31) * 128 + kb];
        short8 b3 = *(const short8*)&Wt[(3 * 32 + l31) * 128 + kb];
        acc0 = __builtin_amdgcn_mfma_f32_32x32x16_bf16(a, b0, acc0, 0, 0, 0);
        acc1 = __builtin_amdgcn_mfma_f32_32x32x16_bf16(a, b1, acc1, 0, 0, 0);
        acc2 = __builtin_amdgcn_mfma_f32_32x32x16_bf16(a, b2, acc2, 0, 0, 0);
        acc3 = __builtin_amdgcn_mfma_f32_32x32x16_bf16(a, b3, acc3, 0, 0, 0);
    }
#pragma unroll
    for (int reg = 0; reg < 16; ++reg) {
        int row = row0 + (reg & 3) + 8 * (reg >> 2) + 4 * lh;
        if (row < M) {
            size_t rb = (size_t)row * 128;
            h[rb +  0 + l31] = (unsigned short)f2bf(acc0[reg]);
            h[rb + 32 + l31] = (unsigned short)f2bf(acc1[reg]);
            h[rb + 64 + l31] = (unsigned short)f2bf(acc2[reg]);
            h[rb + 96 + l31] = (unsigned short)f2bf(acc3[reg]);
        }
    }
}

// ---------------- fused: binA (LDS counting-sort) + att ----------------
__global__ __launch_bounds__(256) void k_binA_att(
        const int* __restrict__ ei, int E, int N, int nps, float inv_nps,
        const int* __restrict__ frag, unsigned* __restrict__ pairs, int chunk,
        const unsigned short* __restrict__ h,
        const float* __restrict__ att_s, const float* __restrict__ att_d,
        float* __restrict__ as, float* __restrict__ ad) {
    __shared__ int cur[NB];
    __shared__ unsigned osort[OSCAP];
    int bid = (int)blockIdx.x;
    int tid = threadIdx.x;

    if (bid < NBLK) {
        int base0 = frag[bid * NB];
        cur[tid] = frag[bid * NB + tid] - base0;
        __syncthreads();
        int total = E + N;
        int lo = bid * chunk;
        int hi = lo + chunk; if (hi > total) hi = total;
        for (int t = lo + tid; t < hi; t += 256) {
            int s, d;
            if (t < E) { s = ei[t]; d = ei[E + t]; }
            else       { s = t - E; d = s; }
            if ((unsigned)s >= (unsigned)N || (unsigned)d >= (unsigned)N) continue;
            int b = bucket_of(d, nps, inv_nps);
            int pos = atomicAdd(&cur[b], 1);
            osort[pos] = ((unsigned)s << 9) | (unsigned)(d - b * nps);
        }
        __syncthreads();
        int m = cur[NB - 1];
        for (int j = tid; j < m; j += 256)
            pairs[base0 + j] = osort[j];
        return;
    }

    // ---- att role ----
    int g = (bid - NBLK) * 256 + tid;
    int n = g >> 6;
    int j = g & 63;
    if (n >= N) return;
    unsigned u = ((const unsigned*)h)[(size_t)n * 64 + j];
    float lo = bflo(u), hi = bfhi(u);
    float ps = lo * att_s[2 * j] + hi * att_s[2 * j + 1];
    float pd = lo * att_d[2 * j] + hi * att_d[2 * j + 1];
#pragma unroll
    for (int off = 8; off >= 1; off >>= 1) {
        ps += __shfl_xor(ps, off, 64);
        pd += __shfl_xor(pd, off, 64);
    }
    if ((j & 15) == 0) {
        int hh = j >> 4;
        as[n * 4 + hh] = ps;
        ad[n * 4 + hh] = pd;
    }
}

// ---------------- binB: fragment-owner threads -> global csrc + rowptr ------
__global__ __launch_bounds__(256) void k_binB(
        const unsigned* __restrict__ pairs,
        const int* __restrict__ cntT, const int* __restrict__ frag,
        const int* __restrict__ bucketBase,
        int* __restrict__ csrc, int* __restrict__ rowptr,
        int N, int nps) {
    __shared__ int hist[512];
    __shared__ int rpt[512];
    __shared__ int sm[256];
    int b = (int)blockIdx.x;
    int t = threadIdx.x;
    int fo = frag[t * NB + b];
    int fc = cntT[b * NBLK + t];
    hist[t] = 0; hist[t + 256] = 0;
    __syncthreads();

    for (int j = 0; j < fc; ++j)
        atomicAdd(&hist[pairs[fo + j] & 511], 1);
    __syncthreads();

    int e0 = hist[2 * t], e1 = hist[2 * t + 1];
    int ps2 = e0 + e1;
    sm[t] = ps2;
    __syncthreads();
    int acc = ps2;
    for (int off = 1; off < 256; off <<= 1) {
        int o = (t >= (unsigned)off) ? sm[t - off] : 0;
        __syncthreads();
        acc += o; sm[t] = acc; __syncthreads();
    }
    int excl = acc - ps2;
    rpt[2 * t] = excl;
    rpt[2 * t + 1] = excl + e0;
    __syncthreads();
    hist[t] = rpt[t]; hist[t + 256] = rpt[t + 256];
    __syncthreads();

    int bbase = bucketBase[b];
    for (int j = 0; j < fc; ++j) {
        unsigned pk = pairs[fo + j];
        int pos = atomicAdd(&hist[pk & 511], 1);
        csrc[bbase + pos] = (int)(pk >> 9);
    }

    for (int k = t; k < nps; k += 256) {
        int n = b * nps + k;
        if (n < N) rowptr[n] = bbase + rpt[k];
    }
    if (b == NB - 1 && t == 0) rowptr[N] = bucketBase[NB];
}

// ---------------- aggregate: 8 edges in flight (eighth-wave, 2x uint4) ------
__global__ __launch_bounds__(256) void k_agg(const unsigned short* __restrict__ h,
                                             const int* __restrict__ rowptr, const int* __restrict__ csrc,
                                             const float* __restrict__ as, const float* __restrict__ ad,
                                             const float* __restrict__ bias,
                                             float* __restrict__ out, int N) {
    int wv = threadIdx.x >> 6;
    int lane = threadIdx.x & 63;
    int n = blockIdx.x * 4 + wv;
    if (n >= N) return;
    int og = lane >> 3;            // edge slot 0..7
    int q8 = lane & 7;             // dims 16*q8 .. 16*q8+15
    int head = q8 >> 1;

    int o0 = rowptr[n];
    int deg = rowptr[n + 1] - o0;
    float adh = ad[(size_t)n * 4 + head];

    const uint4* hp = (const uint4*)h;   // 16 uint4 per row
    float a[16];
#pragma unroll
    for (int j = 0; j < 16; ++j) a[j] = 0.f;
    float sw = 0.f;

    for (int i = og; i < deg; i += 8) {
        int s = csrc[o0 + i];
        float e = lrelu(as[(size_t)s * 4 + head] + adh);
        float w = __expf(e);
        uint4 u0 = hp[(size_t)s * 16 + 2 * q8];
        uint4 u1 = hp[(size_t)s * 16 + 2 * q8 + 1];
        a[0]  = fmaf(w, bflo(u0.x), a[0]);  a[1]  = fmaf(w, bfhi(u0.x), a[1]);
        a[2]  = fmaf(w, bflo(u0.y), a[2]);  a[3]  = fmaf(w, bfhi(u0.y), a[3]);
        a[4]  = fmaf(w, bflo(u0.z), a[4]);  a[5]  = fmaf(w, bfhi(u0.z), a[5]);
        a[6]  = fmaf(w, bflo(u0.w), a[6]);  a[7]  = fmaf(w, bfhi(u0.w), a[7]);
        a[8]  = fmaf(w, bflo(u1.x), a[8]);  a[9]  = fmaf(w, bfhi(u1.x), a[9]);
        a[10] = fmaf(w, bflo(u1.y), a[10]); a[11] = fmaf(w, bfhi(u1.y), a[11]);
        a[12] = fmaf(w, bflo(u1.z), a[12]); a[13] = fmaf(w, bfhi(u1.z), a[13]);
        a[14] = fmaf(w, bflo(u1.w), a[14]); a[15] = fmaf(w, bfhi(u1.w), a[15]);
        sw += w;
    }
#pragma unroll
    for (int j = 0; j < 16; ++j) {
        a[j] += __shfl_xor(a[j], 8, 64);
        a[j] += __shfl_xor(a[j], 16, 64);
        a[j] += __shfl_xor(a[j], 32, 64);
    }
    sw += __shfl_xor(sw, 8, 64);
    sw += __shfl_xor(sw, 16, 64);
    sw += __shfl_xor(sw, 32, 64);

    if (og == 0) {
        float inv = 1.f / (sw + 1e-16f);
        int d0 = q8 * 16;
        float* ob = &out[(size_t)n * 128 + d0];
#pragma unroll
        for (int c4 = 0; c4 < 4; ++c4) {
            float4 bv = *(const float4*)&bias[d0 + c4 * 4];
            float r0 = fmaf(a[c4 * 4 + 0], inv, bv.x);
            float r1 = fmaf(a[c4 * 4 + 1], inv, bv.y);
            float r2 = fmaf(a[c4 * 4 + 2], inv, bv.z);
            float r3 = fmaf(a[c4 * 4 + 3], inv, bv.w);
            r0 = r0 > 0.f ? r0 : __expf(r0) - 1.f;
            r1 = r1 > 0.f ? r1 : __expf(r1) - 1.f;
            r2 = r2 > 0.f ? r2 : __expf(r2) - 1.f;
            r3 = r3 > 0.f ? r3 : __expf(r3) - 1.f;
            *(float4*)&ob[c4 * 4] = make_float4(r0, r1, r2, r3);
        }
    }
}

// ---------------- launch ----------------
extern "C" void kernel_launch(void* const* d_in, const int* in_sizes, int n_in,
                              void* d_out, int out_size, void* d_ws, size_t ws_size,
                              hipStream_t stream) {
    const float* x     = (const float*)d_in[0];
    const int*   ei    = (const int*)d_in[1];     // int32 [2][E] flat
    const float* W     = (const float*)d_in[2];
    const float* att_s = (const float*)d_in[3];
    const float* att_d = (const float*)d_in[4];
    const float* bias  = (const float*)d_in[5];
    float* out = (float*)d_out;

    int N = in_sizes[0] / 128;
    int E = in_sizes[1] / 2;
    int total = E + N;

    int nps = (N + NB - 1) / NB;                  // 391 (<512 for 9-bit pack)
    float inv_nps = 1.0f / (float)nps;
    int chunk = (total + NBLK - 1) / NBLK;        // ~6641 (<= OSCAP)

    auto align256 = [](size_t v) { return (v + 255) & ~(size_t)255; };
    char* wsp = (char*)d_ws;
    size_t off = 0;
    auto alloc = [&](size_t bytes) {
        char* p = wsp + off;
        off += align256(bytes);
        return p;
    };
    unsigned short* h  = (unsigned short*)alloc((size_t)N * 128 * 2);
    unsigned short* Wt = (unsigned short*)alloc(128 * 128 * 2);
    float* as        = (float*)alloc((size_t)N * 16);
    float* ad        = (float*)alloc((size_t)N * 16);
    int*   cntT      = (int*)alloc((size_t)NB * NBLK * 4);
    int*   frag      = (int*)alloc((size_t)NBLK * NB * 4);
    int*   rowTot    = (int*)alloc((size_t)NBLK * 4);
    int*   bucketBase= (int*)alloc((size_t)(NB + 1) * 4);
    unsigned* pairs  = (unsigned*)alloc((size_t)total * 4);
    int*   csrc      = (int*)alloc((size_t)total * 4);
    int*   rowptr    = (int*)alloc((size_t)(N + 1) * 4);
    (void)ws_size;

    int nGemm = (N + 127) / 128;                  // 782
    int nAtt  = ((size_t)N * 64 + 255) / 256;     // 25000

    k_countA<<<NBLK, 256, 0, stream>>>(W, Wt, ei, E, N, nps, inv_nps, cntT, frag, rowTot, chunk);
    k_gemm_scanR<<<1 + nGemm, 256, 0, stream>>>(x, Wt, h, N, rowTot, frag, cntT, bucketBase);
    k_binA_att<<<NBLK + nAtt, 256, 0, stream>>>(ei, E, N, nps, inv_nps, frag, pairs, chunk,
                                                h, att_s, att_d, as, ad);
    k_binB<<<NB, 256, 0, stream>>>(pairs, cntT, frag, bucketBase, csrc, rowptr, N, nps);
    k_agg<<<(N + 3) / 4, 256, 0, stream>>>(h, rowptr, csrc, as, ad, bias, out, N);
}

// Round 15
// 174.809 us; speedup vs baseline: 1.2975x; 1.2403x over previous
//
#include <hip/hip_runtime.h>
#include <math.h>

#define NEG_SLOPE_F 0.2f
#define NB    256     // dst buckets
#define NBLK  256     // binning chunk blocks
#define OSCAP 6912    // binA LDS sort cap >= chunk

typedef __attribute__((ext_vector_type(8)))  short short8;
typedef __attribute__((ext_vector_type(16))) float f32x16;

static __device__ __forceinline__ float lrelu(float x) {
    return x > 0.f ? x : NEG_SLOPE_F * x;
}
static __device__ __forceinline__ unsigned f2bf(float f) {
    unsigned u = __float_as_uint(f);
    return (u + 0x7FFFu + ((u >> 16) & 1u)) >> 16;
}
static __device__ __forceinline__ float bflo(unsigned w) { return __uint_as_float(w << 16); }
static __device__ __forceinline__ float bfhi(unsigned w) { return __uint_as_float(w & 0xFFFF0000u); }

static __device__ __forceinline__ int bucket_of(int d, int nps, float inv_nps) {
    int b = (int)((float)d * inv_nps);
    if (d < b * nps) --b;
    else if (d >= (b + 1) * nps) ++b;
    return b;
}

// ---------------- countA (+Wt init in first 64 blocks) ----------------
// Outputs: cntT[b*NBLK+blk], fragRow[blk*NB+b] (LOCAL exclusive), rowTot[blk].
__global__ __launch_bounds__(256) void k_countA(const float* __restrict__ W, unsigned short* __restrict__ Wt,
                                                const int* __restrict__ ei, int E, int N,
                                                int nps, float inv_nps,
                                                int* __restrict__ cntT, int* __restrict__ fragRow,
                                                int* __restrict__ rowTot, int chunk) {
    __shared__ int hist[NB];
    __shared__ int sm[NB];
    int bid = blockIdx.x, tid = threadIdx.x;
    if (bid < 64) {
        int g = bid * 256 + tid;
        int c = g >> 7, k = g & 127;
        Wt[c * 128 + k] = (unsigned short)f2bf(W[k * 128 + c]);
    }
    hist[tid] = 0;
    __syncthreads();
    int total = E + N;
    int lo = bid * chunk;
    int hi = lo + chunk; if (hi > total) hi = total;
    for (int t = lo + tid; t < hi; t += 256) {
        int s, d;
        if (t < E) { s = ei[t]; d = ei[E + t]; }
        else       { s = t - E; d = s; }
        if ((unsigned)s >= (unsigned)N || (unsigned)d >= (unsigned)N) continue;
        atomicAdd(&hist[bucket_of(d, nps, inv_nps)], 1);
    }
    __syncthreads();
    int v = hist[tid];
    sm[tid] = v;
    __syncthreads();
    int acc = v;
    for (int off = 1; off < 256; off <<= 1) {
        int o = (tid >= (unsigned)off) ? sm[tid - off] : 0;
        __syncthreads();
        acc += o; sm[tid] = acc; __syncthreads();
    }
    fragRow[bid * NB + tid] = acc - v;             // local exclusive
    cntT[tid * NBLK + bid] = v;
    if (tid == 255) rowTot[bid] = acc;
}

// ---------------- fused: binA [0,NBLK) + bucketBase (NBLK) + MFMA GEMM ------
// binA computes its own blockBase via an in-block scan of rowTot (no scanR).
__global__ __launch_bounds__(256) void k_gemm_binA(
        const float* __restrict__ x, const unsigned short* __restrict__ Wt,
        unsigned short* __restrict__ h, int M,
        const int* __restrict__ ei, int E, int N, int nps, float inv_nps,
        const int* __restrict__ fragRow, const int* __restrict__ rowTot,
        const int* __restrict__ cntT, int* __restrict__ bucketBase,
        unsigned* __restrict__ pairs, int chunk) {
    int bid = (int)blockIdx.x;
    int tid = threadIdx.x;

    if (bid < NBLK) {
        // ---- binA ----
        __shared__ int sm[256];
        __shared__ int bb[256];
        __shared__ int cur[NB];
        __shared__ unsigned osort[OSCAP];
        int v = rowTot[tid];
        sm[tid] = v; __syncthreads();
        int acc = v;
        for (int off = 1; off < 256; off <<= 1) {
            int o = (tid >= (unsigned)off) ? sm[tid - off] : 0;
            __syncthreads();
            acc += o; sm[tid] = acc; __syncthreads();
        }
        bb[tid] = acc - v;
        cur[tid] = fragRow[bid * NB + tid];
        __syncthreads();
        int base0 = bb[bid];

        int total = E + N;
        int lo = bid * chunk;
        int hi = lo + chunk; if (hi > total) hi = total;
        for (int t = lo + tid; t < hi; t += 256) {
            int s, d;
            if (t < E) { s = ei[t]; d = ei[E + t]; }
            else       { s = t - E; d = s; }
            if ((unsigned)s >= (unsigned)N || (unsigned)d >= (unsigned)N) continue;
            int b = bucket_of(d, nps, inv_nps);
            int pos = atomicAdd(&cur[b], 1);
            osort[pos] = ((unsigned)s << 9) | (unsigned)(d - b * nps);
        }
        __syncthreads();
        int m = cur[NB - 1];
        for (int j = tid; j < m; j += 256)
            pairs[base0 + j] = osort[j];
        return;
    }

    if (bid == NBLK) {
        // ---- bucketBase: column sums + scan ----
        __shared__ int sm[256];
        int cv = 0;
        const int* row = cntT + tid * NBLK;
        for (int i = 0; i < NBLK; ++i) cv += row[i];
        sm[tid] = cv; __syncthreads();
        int acc2 = cv;
        for (int off = 1; off < 256; off <<= 1) {
            int o = (tid >= (unsigned)off) ? sm[tid - off] : 0;
            __syncthreads();
            acc2 += o; sm[tid] = acc2; __syncthreads();
        }
        bucketBase[tid] = acc2 - cv;
        if (tid == 255) bucketBase[NB] = acc2;
        return;
    }

    // ---- MFMA GEMM: 128x128 per block, 4 waves x 32 rows ----
    int w = tid >> 6;
    int lane = tid & 63;
    int l31 = lane & 31;
    int lh = lane >> 5;
    int row0 = (bid - NBLK - 1) * 128 + w * 32;

    f32x16 acc0, acc1, acc2, acc3;
#pragma unroll
    for (int i = 0; i < 16; ++i) { acc0[i] = 0.f; acc1[i] = 0.f; acc2[i] = 0.f; acc3[i] = 0.f; }

    int arow = row0 + l31;
    if (arow >= M) arow = M - 1;

    for (int k0 = 0; k0 < 128; k0 += 16) {
        int kb = k0 + lh * 8;
        float4 v0 = *(const float4*)&x[(size_t)arow * 128 + kb];
        float4 v1 = *(const float4*)&x[(size_t)arow * 128 + kb + 4];
        short8 a;
        a[0] = (short)f2bf(v0.x); a[1] = (short)f2bf(v0.y);
        a[2] = (short)f2bf(v0.z); a[3] = (short)f2bf(v0.w);
        a[4] = (short)f2bf(v1.x); a[5] = (short)f2bf(v1.y);
        a[6] = (short)f2bf(v1.z); a[7] = (short)f2bf(v1.w);
        short8 b0 = *(const short8*)&Wt[(0 * 32 + l31) * 128 + kb];
        short8 b1 = *(const short8*)&Wt[(1 * 32 + l31) * 128 + kb];
        short8 b2 = *(const short8*)&Wt[(2 * 32 + l31) * 128 + kb];
        short8 b3 = *(const short8*)&Wt[(3 * 32 + l31) * 128 + kb];
        acc0 = __builtin_amdgcn_mfma_f32_32x32x16_bf16(a, b0, acc0, 0, 0, 0);
        acc1 = __builtin_amdgcn_mfma_f32_32x32x16_bf16(a, b1, acc1, 0, 0, 0);
        acc2 = __builtin_amdgcn_mfma_f32_32x32x16_bf16(a, b2, acc2, 0, 0, 0);
        acc3 = __builtin_amdgcn_mfma_f32_32x32x16_bf16(a, b3, acc3, 0, 0, 0);
    }
#pragma unroll
    for (int reg = 0; reg < 16; ++reg) {
        int row = row0 + (reg & 3) + 8 * (reg >> 2) + 4 * lh;
        if (row < M) {
            size_t rb = (size_t)row * 128;
            h[rb +  0 + l31] = (unsigned short)f2bf(acc0[reg]);
            h[rb + 32 + l31] = (unsigned short)f2bf(acc1[reg]);
            h[rb + 64 + l31] = (unsigned short)f2bf(acc2[reg]);
            h[rb + 96 + l31] = (unsigned short)f2bf(acc3[reg]);
        }
    }
}

// ---------------- fused: binB [0,NB) + att ----------------
__global__ __launch_bounds__(256) void k_binB_att(
        const unsigned* __restrict__ pairs,
        const int* __restrict__ cntT, const int* __restrict__ fragRow,
        const int* __restrict__ rowTot, const int* __restrict__ bucketBase,
        int* __restrict__ csrc, int* __restrict__ rowptr,
        const unsigned short* __restrict__ h,
        const float* __restrict__ att_s, const float* __restrict__ att_d,
        float* __restrict__ as, float* __restrict__ ad,
        int N, int nps) {
    int bid = (int)blockIdx.x;
    int t = threadIdx.x;

    if (bid >= NB) {
        // ---- att role ----
        int g = (bid - NB) * 256 + t;
        int n = g >> 6;
        int j = g & 63;
        if (n >= N) return;
        unsigned u = ((const unsigned*)h)[(size_t)n * 64 + j];
        float lo = bflo(u), hi = bfhi(u);
        float ps = lo * att_s[2 * j] + hi * att_s[2 * j + 1];
        float pd = lo * att_d[2 * j] + hi * att_d[2 * j + 1];
#pragma unroll
        for (int off = 8; off >= 1; off >>= 1) {
            ps += __shfl_xor(ps, off, 64);
            pd += __shfl_xor(pd, off, 64);
        }
        if ((j & 15) == 0) {
            int hh = j >> 4;
            as[n * 4 + hh] = ps;
            ad[n * 4 + hh] = pd;
        }
        return;
    }

    // ---- binB role ----
    __shared__ int hist[512];
    __shared__ int rpt[512];
    __shared__ int sm[256];
    __shared__ int bb[256];
    int b = bid;

    // in-block blockBase from rowTot
    int v = rowTot[t];
    sm[t] = v; __syncthreads();
    int acc0 = v;
    for (int off = 1; off < 256; off <<= 1) {
        int o = (t >= (unsigned)off) ? sm[t - off] : 0;
        __syncthreads();
        acc0 += o; sm[t] = acc0; __syncthreads();
    }
    bb[t] = acc0 - v;
    hist[t] = 0; hist[t + 256] = 0;
    __syncthreads();

    int fo = bb[t] + fragRow[t * NB + b];
    int fc = cntT[b * NBLK + t];

    for (int j = 0; j < fc; ++j)
        atomicAdd(&hist[pairs[fo + j] & 511], 1);
    __syncthreads();

    int e0 = hist[2 * t], e1 = hist[2 * t + 1];
    int ps2 = e0 + e1;
    sm[t] = ps2;
    __syncthreads();
    int acc = ps2;
    for (int off = 1; off < 256; off <<= 1) {
        int o = (t >= (unsigned)off) ? sm[t - off] : 0;
        __syncthreads();
        acc += o; sm[t] = acc; __syncthreads();
    }
    int excl = acc - ps2;
    rpt[2 * t] = excl;
    rpt[2 * t + 1] = excl + e0;
    __syncthreads();
    hist[t] = rpt[t]; hist[t + 256] = rpt[t + 256];
    __syncthreads();

    int bbase = bucketBase[b];
    for (int j = 0; j < fc; ++j) {
        unsigned pk = pairs[fo + j];
        int pos = atomicAdd(&hist[pk & 511], 1);
        csrc[bbase + pos] = (int)(pk >> 9);
    }

    for (int k = t; k < nps; k += 256) {
        int n = b * nps + k;
        if (n < N) rowptr[n] = bbase + rpt[k];
    }
    if (b == NB - 1 && t == 0) rowptr[N] = bucketBase[NB];
}

// ---------------- aggregate: 8 edges in flight (eighth-wave, 2x uint4) ------
__global__ __launch_bounds__(256) void k_agg(const unsigned short* __restrict__ h,
                                             const int* __restrict__ rowptr, const int* __restrict__ csrc,
                                             const float* __restrict__ as, const float* __restrict__ ad,
                                             const float* __restrict__ bias,
                                             float* __restrict__ out, int N) {
    int wv = threadIdx.x >> 6;
    int lane = threadIdx.x & 63;
    int n = blockIdx.x * 4 + wv;
    if (n >= N) return;
    int og = lane >> 3;            // edge slot 0..7
    int q8 = lane & 7;             // dims 16*q8 .. 16*q8+15
    int head = q8 >> 1;

    int o0 = rowptr[n];
    int deg = rowptr[n + 1] - o0;
    float adh = ad[(size_t)n * 4 + head];

    const uint4* hp = (const uint4*)h;   // 16 uint4 per row
    float a[16];
#pragma unroll
    for (int j = 0; j < 16; ++j) a[j] = 0.f;
    float sw = 0.f;

    for (int i = og; i < deg; i += 8) {
        int s = csrc[o0 + i];
        float e = lrelu(as[(size_t)s * 4 + head] + adh);
        float w = __expf(e);
        uint4 u0 = hp[(size_t)s * 16 + 2 * q8];
        uint4 u1 = hp[(size_t)s * 16 + 2 * q8 + 1];
        a[0]  = fmaf(w, bflo(u0.x), a[0]);  a[1]  = fmaf(w, bfhi(u0.x), a[1]);
        a[2]  = fmaf(w, bflo(u0.y), a[2]);  a[3]  = fmaf(w, bfhi(u0.y), a[3]);
        a[4]  = fmaf(w, bflo(u0.z), a[4]);  a[5]  = fmaf(w, bfhi(u0.z), a[5]);
        a[6]  = fmaf(w, bflo(u0.w), a[6]);  a[7]  = fmaf(w, bfhi(u0.w), a[7]);
        a[8]  = fmaf(w, bflo(u1.x), a[8]);  a[9]  = fmaf(w, bfhi(u1.x), a[9]);
        a[10] = fmaf(w, bflo(u1.y), a[10]); a[11] = fmaf(w, bfhi(u1.y), a[11]);
        a[12] = fmaf(w, bflo(u1.z), a[12]); a[13] = fmaf(w, bfhi(u1.z), a[13]);
        a[14] = fmaf(w, bflo(u1.w), a[14]); a[15] = fmaf(w, bfhi(u1.w), a[15]);
        sw += w;
    }
#pragma unroll
    for (int j = 0; j < 16; ++j) {
        a[j] += __shfl_xor(a[j], 8, 64);
        a[j] += __shfl_xor(a[j], 16, 64);
        a[j] += __shfl_xor(a[j], 32, 64);
    }
    sw += __shfl_xor(sw, 8, 64);
    sw += __shfl_xor(sw, 16, 64);
    sw += __shfl_xor(sw, 32, 64);

    if (og == 0) {
        float inv = 1.f / (sw + 1e-16f);
        int d0 = q8 * 16;
        float* ob = &out[(size_t)n * 128 + d0];
#pragma unroll
        for (int c4 = 0; c4 < 4; ++c4) {
            float4 bv = *(const float4*)&bias[d0 + c4 * 4];
            float r0 = fmaf(a[c4 * 4 + 0], inv, bv.x);
            float r1 = fmaf(a[c4 * 4 + 1], inv, bv.y);
            float r2 = fmaf(a[c4 * 4 + 2], inv, bv.z);
            float r3 = fmaf(a[c4 * 4 + 3], inv, bv.w);
            r0 = r0 > 0.f ? r0 : __expf(r0) - 1.f;
            r1 = r1 > 0.f ? r1 : __expf(r1) - 1.f;
            r2 = r2 > 0.f ? r2 : __expf(r2) - 1.f;
            r3 = r3 > 0.f ? r3 : __expf(r3) - 1.f;
            *(float4*)&ob[c4 * 4] = make_float4(r0, r1, r2, r3);
        }
    }
}

// ---------------- launch ----------------
extern "C" void kernel_launch(void* const* d_in, const int* in_sizes, int n_in,
                              void* d_out, int out_size, void* d_ws, size_t ws_size,
                              hipStream_t stream) {
    const float* x     = (const float*)d_in[0];
    const int*   ei    = (const int*)d_in[1];     // int32 [2][E] flat
    const float* W     = (const float*)d_in[2];
    const float* att_s = (const float*)d_in[3];
    const float* att_d = (const float*)d_in[4];
    const float* bias  = (const float*)d_in[5];
    float* out = (float*)d_out;

    int N = in_sizes[0] / 128;
    int E = in_sizes[1] / 2;
    int total = E + N;

    int nps = (N + NB - 1) / NB;                  // 391 (<512 for 9-bit pack)
    float inv_nps = 1.0f / (float)nps;
    int chunk = (total + NBLK - 1) / NBLK;        // ~6641 (<= OSCAP)

    auto align256 = [](size_t v) { return (v + 255) & ~(size_t)255; };
    char* wsp = (char*)d_ws;
    size_t off = 0;
    auto alloc = [&](size_t bytes) {
        char* p = wsp + off;
        off += align256(bytes);
        return p;
    };
    unsigned short* h  = (unsigned short*)alloc((size_t)N * 128 * 2);
    unsigned short* Wt = (unsigned short*)alloc(128 * 128 * 2);
    float* as        = (float*)alloc((size_t)N * 16);
    float* ad        = (float*)alloc((size_t)N * 16);
    int*   cntT      = (int*)alloc((size_t)NB * NBLK * 4);
    int*   fragRow   = (int*)alloc((size_t)NBLK * NB * 4);
    int*   rowTot    = (int*)alloc((size_t)NBLK * 4);
    int*   bucketBase= (int*)alloc((size_t)(NB + 1) * 4);
    unsigned* pairs  = (unsigned*)alloc((size_t)total * 4);
    int*   csrc      = (int*)alloc((size_t)total * 4);
    int*   rowptr    = (int*)alloc((size_t)(N + 1) * 4);
    (void)ws_size;

    int nGemm = (N + 127) / 128;                  // 782
    int nAtt  = ((size_t)N * 64 + 255) / 256;     // 25000

    k_countA<<<NBLK, 256, 0, stream>>>(W, Wt, ei, E, N, nps, inv_nps, cntT, fragRow, rowTot, chunk);
    k_gemm_binA<<<NBLK + 1 + nGemm, 256, 0, stream>>>(x, Wt, h, N, ei, E, N, nps, inv_nps,
                                                      fragRow, rowTot, cntT, bucketBase,
                                                      pairs, chunk);
    k_binB_att<<<NB + nAtt, 256, 0, stream>>>(pairs, cntT, fragRow, rowTot, bucketBase,
                                              csrc, rowptr, h, att_s, att_d, as, ad, N, nps);
    k_agg<<<(N + 3) / 4, 256, 0, stream>>>(h, rowptr, csrc, as, ad, bias, out, N);
}

// Round 16
// 165.430 us; speedup vs baseline: 1.3711x; 1.0567x over previous
//
#include <hip/hip_runtime.h>
#include <math.h>

#define NEG_SLOPE_F 0.2f
#define NB    256     // dst buckets
#define NBLK  256     // binning chunk blocks
#define OSCAP 6912    // LDS sort cap >= chunk

typedef __attribute__((ext_vector_type(8)))  short short8;
typedef __attribute__((ext_vector_type(16))) float f32x16;

static __device__ __forceinline__ float lrelu(float x) {
    return x > 0.f ? x : NEG_SLOPE_F * x;
}
static __device__ __forceinline__ unsigned f2bf(float f) {
    unsigned u = __float_as_uint(f);
    return (u + 0x7FFFu + ((u >> 16) & 1u)) >> 16;
}
static __device__ __forceinline__ float bflo(unsigned w) { return __uint_as_float(w << 16); }
static __device__ __forceinline__ float bfhi(unsigned w) { return __uint_as_float(w & 0xFFFF0000u); }

static __device__ __forceinline__ int bucket_of(int d, int nps, float inv_nps) {
    int b = (int)((float)d * inv_nps);
    if (d < b * nps) --b;
    else if (d >= (b + 1) * nps) ++b;
    return b;
}

// ---------------- fused L1: countSort (blocks [0,NBLK)) + MFMA GEMM ---------
// countSort: per chunk-block counting sort entirely in LDS; pairs written to
// the BLOCK-LOCAL region pairs[bid*chunk ...] (no global offsets needed).
// GEMM: h_bf16 = bf16(x)@bf16(W), W read directly (coalesced per-j rows).
__global__ __launch_bounds__(256) void k_gemm_sortA(
        const float* __restrict__ x, const float* __restrict__ W,
        unsigned short* __restrict__ h, int M,
        const int* __restrict__ ei, int E, int N, int nps, float inv_nps,
        int* __restrict__ cntT, int* __restrict__ fragRow,
        unsigned* __restrict__ pairs, int chunk) {
    int bid = (int)blockIdx.x;
    int tid = threadIdx.x;

    if (bid < NBLK) {
        // ---- counting sort of this block's edge chunk ----
        __shared__ int hist[NB];
        __shared__ int sm[NB];
        __shared__ int cur[NB];
        __shared__ unsigned osort[OSCAP];
        hist[tid] = 0;
        __syncthreads();
        int total = E + N;
        int lo = bid * chunk;
        int hi = lo + chunk; if (hi > total) hi = total;
        for (int t = lo + tid; t < hi; t += 256) {
            int s, d;
            if (t < E) { s = ei[t]; d = ei[E + t]; }
            else       { s = t - E; d = s; }
            if ((unsigned)s >= (unsigned)N || (unsigned)d >= (unsigned)N) continue;
            atomicAdd(&hist[bucket_of(d, nps, inv_nps)], 1);
        }
        __syncthreads();
        int v = hist[tid];
        sm[tid] = v;
        __syncthreads();
        int acc = v;
        for (int off = 1; off < 256; off <<= 1) {
            int o = (tid >= (unsigned)off) ? sm[tid - off] : 0;
            __syncthreads();
            acc += o; sm[tid] = acc; __syncthreads();
        }
        int excl = acc - v;
        fragRow[bid * NB + tid] = excl;        // local exclusive offset
        cntT[tid * NBLK + bid] = v;            // bucket-major counts
        cur[tid] = excl;
        __syncthreads();
        // pass 2: scatter (edges L2-warm from pass 1)
        for (int t = lo + tid; t < hi; t += 256) {
            int s, d;
            if (t < E) { s = ei[t]; d = ei[E + t]; }
            else       { s = t - E; d = s; }
            if ((unsigned)s >= (unsigned)N || (unsigned)d >= (unsigned)N) continue;
            int b = bucket_of(d, nps, inv_nps);
            int pos = atomicAdd(&cur[b], 1);
            osort[pos] = ((unsigned)s << 9) | (unsigned)(d - b * nps);
        }
        __syncthreads();
        int m = cur[NB - 1];
        unsigned* pout = pairs + (size_t)bid * chunk;
        for (int j = tid; j < m; j += 256)
            pout[j] = osort[j];                // coalesced block-local stream
        return;
    }

    // ---- MFMA GEMM: 128x128 per block, 4 waves x 32 rows, W read direct ----
    int gb = bid - NBLK;
    int w = tid >> 6;
    int lane = tid & 63;
    int l31 = lane & 31;
    int lh = lane >> 5;
    int row0 = gb * 128 + w * 32;

    f32x16 acc0, acc1, acc2, acc3;
#pragma unroll
    for (int i = 0; i < 16; ++i) { acc0[i] = 0.f; acc1[i] = 0.f; acc2[i] = 0.f; acc3[i] = 0.f; }

    int arow = row0 + l31;
    if (arow >= M) arow = M - 1;

    for (int k0 = 0; k0 < 128; k0 += 16) {
        int kb = k0 + lh * 8;
        float4 v0 = *(const float4*)&x[(size_t)arow * 128 + kb];
        float4 v1 = *(const float4*)&x[(size_t)arow * 128 + kb + 4];
        short8 a;
        a[0] = (short)f2bf(v0.x); a[1] = (short)f2bf(v0.y);
        a[2] = (short)f2bf(v0.z); a[3] = (short)f2bf(v0.w);
        a[4] = (short)f2bf(v1.x); a[5] = (short)f2bf(v1.y);
        a[6] = (short)f2bf(v1.z); a[7] = (short)f2bf(v1.w);
        short8 b0, b1, b2, b3;
#pragma unroll
        for (int j = 0; j < 8; ++j) {
            const float* wr = &W[(size_t)(kb + j) * 128];
            b0[j] = (short)f2bf(wr[  0 + l31]);
            b1[j] = (short)f2bf(wr[ 32 + l31]);
            b2[j] = (short)f2bf(wr[ 64 + l31]);
            b3[j] = (short)f2bf(wr[ 96 + l31]);
        }
        acc0 = __builtin_amdgcn_mfma_f32_32x32x16_bf16(a, b0, acc0, 0, 0, 0);
        acc1 = __builtin_amdgcn_mfma_f32_32x32x16_bf16(a, b1, acc1, 0, 0, 0);
        acc2 = __builtin_amdgcn_mfma_f32_32x32x16_bf16(a, b2, acc2, 0, 0, 0);
        acc3 = __builtin_amdgcn_mfma_f32_32x32x16_bf16(a, b3, acc3, 0, 0, 0);
    }
#pragma unroll
    for (int reg = 0; reg < 16; ++reg) {
        int row = row0 + (reg & 3) + 8 * (reg >> 2) + 4 * lh;
        if (row < M) {
            size_t rb = (size_t)row * 128;
            h[rb +  0 + l31] = (unsigned short)f2bf(acc0[reg]);
            h[rb + 32 + l31] = (unsigned short)f2bf(acc1[reg]);
            h[rb + 64 + l31] = (unsigned short)f2bf(acc2[reg]);
            h[rb + 96 + l31] = (unsigned short)f2bf(acc3[reg]);
        }
    }
}

// ---------------- fused L2: binB (self-computed bucketBase) + att -----------
__global__ __launch_bounds__(256) void k_binB_att(
        const unsigned* __restrict__ pairs,
        const int* __restrict__ cntT, const int* __restrict__ fragRow,
        int* __restrict__ csrc, int* __restrict__ rowptr,
        const unsigned short* __restrict__ h,
        const float* __restrict__ att_s, const float* __restrict__ att_d,
        float* __restrict__ as, float* __restrict__ ad,
        int N, int nps, int chunk) {
    int bid = (int)blockIdx.x;
    int t = threadIdx.x;

    if (bid >= NB) {
        // ---- att role ----
        int g = (bid - NB) * 256 + t;
        int n = g >> 6;
        int j = g & 63;
        if (n >= N) return;
        unsigned u = ((const unsigned*)h)[(size_t)n * 64 + j];
        float lo = bflo(u), hi = bfhi(u);
        float ps = lo * att_s[2 * j] + hi * att_s[2 * j + 1];
        float pd = lo * att_d[2 * j] + hi * att_d[2 * j + 1];
#pragma unroll
        for (int off = 8; off >= 1; off >>= 1) {
            ps += __shfl_xor(ps, off, 64);
            pd += __shfl_xor(pd, off, 64);
        }
        if ((j & 15) == 0) {
            int hh = j >> 4;
            as[n * 4 + hh] = ps;
            ad[n * 4 + hh] = pd;
        }
        return;
    }

    // ---- binB role ----
    __shared__ int hist[512];
    __shared__ int rpt[512];
    __shared__ int sm[256];
    __shared__ int tot_s;
    int b = bid;

    // self bucketBase: sum cntT rows < b (thread t owns blk column t)
    int partial = 0;
#pragma unroll 8
    for (int bp = 0; bp < b; ++bp) partial += cntT[bp * NBLK + t];
    sm[t] = partial;
    __syncthreads();
    for (int off = 128; off >= 1; off >>= 1) {
        if (t < off) sm[t] += sm[t + off];
        __syncthreads();
    }
    int bbase = sm[0];
    __syncthreads();

    hist[t] = 0; hist[t + 256] = 0;
    __syncthreads();

    int fo = t * chunk + fragRow[t * NB + b];
    int fc = cntT[b * NBLK + t];

    for (int j = 0; j < fc; ++j)
        atomicAdd(&hist[pairs[(size_t)fo + j] & 511], 1);
    __syncthreads();

    int e0 = hist[2 * t], e1 = hist[2 * t + 1];
    int ps2 = e0 + e1;
    sm[t] = ps2;
    __syncthreads();
    int acc = ps2;
    for (int off = 1; off < 256; off <<= 1) {
        int o = (t >= (unsigned)off) ? sm[t - off] : 0;
        __syncthreads();
        acc += o; sm[t] = acc; __syncthreads();
    }
    int excl = acc - ps2;
    rpt[2 * t] = excl;
    rpt[2 * t + 1] = excl + e0;
    if (t == 255) tot_s = excl + e0 + e1;
    __syncthreads();
    hist[t] = rpt[t]; hist[t + 256] = rpt[t + 256];
    __syncthreads();

    for (int j = 0; j < fc; ++j) {
        unsigned pk = pairs[(size_t)fo + j];
        int pos = atomicAdd(&hist[pk & 511], 1);
        csrc[bbase + pos] = (int)(pk >> 9);
    }

    for (int k = t; k < nps; k += 256) {
        int n = b * nps + k;
        if (n < N) rowptr[n] = bbase + rpt[k];
    }
    if (b == NB - 1 && t == 0) rowptr[N] = bbase + tot_s;
}

// ---------------- aggregate: 8 edges in flight (eighth-wave, 2x uint4) ------
__global__ __launch_bounds__(256) void k_agg(const unsigned short* __restrict__ h,
                                             const int* __restrict__ rowptr, const int* __restrict__ csrc,
                                             const float* __restrict__ as, const float* __restrict__ ad,
                                             const float* __restrict__ bias,
                                             float* __restrict__ out, int N) {
    int wv = threadIdx.x >> 6;
    int lane = threadIdx.x & 63;
    int n = blockIdx.x * 4 + wv;
    if (n >= N) return;
    int og = lane >> 3;            // edge slot 0..7
    int q8 = lane & 7;             // dims 16*q8 .. 16*q8+15
    int head = q8 >> 1;

    int o0 = rowptr[n];
    int deg = rowptr[n + 1] - o0;
    float adh = ad[(size_t)n * 4 + head];

    const uint4* hp = (const uint4*)h;   // 16 uint4 per row
    float a[16];
#pragma unroll
    for (int j = 0; j < 16; ++j) a[j] = 0.f;
    float sw = 0.f;

    for (int i = og; i < deg; i += 8) {
        int s = csrc[o0 + i];
        float e = lrelu(as[(size_t)s * 4 + head] + adh);
        float w = __expf(e);
        uint4 u0 = hp[(size_t)s * 16 + 2 * q8];
        uint4 u1 = hp[(size_t)s * 16 + 2 * q8 + 1];
        a[0]  = fmaf(w, bflo(u0.x), a[0]);  a[1]  = fmaf(w, bfhi(u0.x), a[1]);
        a[2]  = fmaf(w, bflo(u0.y), a[2]);  a[3]  = fmaf(w, bfhi(u0.y), a[3]);
        a[4]  = fmaf(w, bflo(u0.z), a[4]);  a[5]  = fmaf(w, bfhi(u0.z), a[5]);
        a[6]  = fmaf(w, bflo(u0.w), a[6]);  a[7]  = fmaf(w, bfhi(u0.w), a[7]);
        a[8]  = fmaf(w, bflo(u1.x), a[8]);  a[9]  = fmaf(w, bfhi(u1.x), a[9]);
        a[10] = fmaf(w, bflo(u1.y), a[10]); a[11] = fmaf(w, bfhi(u1.y), a[11]);
        a[12] = fmaf(w, bflo(u1.z), a[12]); a[13] = fmaf(w, bfhi(u1.z), a[13]);
        a[14] = fmaf(w, bflo(u1.w), a[14]); a[15] = fmaf(w, bfhi(u1.w), a[15]);
        sw += w;
    }
#pragma unroll
    for (int j = 0; j < 16; ++j) {
        a[j] += __shfl_xor(a[j], 8, 64);
        a[j] += __shfl_xor(a[j], 16, 64);
        a[j] += __shfl_xor(a[j], 32, 64);
    }
    sw += __shfl_xor(sw, 8, 64);
    sw += __shfl_xor(sw, 16, 64);
    sw += __shfl_xor(sw, 32, 64);

    if (og == 0) {
        float inv = 1.f / (sw + 1e-16f);
        int d0 = q8 * 16;
        float* ob = &out[(size_t)n * 128 + d0];
#pragma unroll
        for (int c4 = 0; c4 < 4; ++c4) {
            float4 bv = *(const float4*)&bias[d0 + c4 * 4];
            float r0 = fmaf(a[c4 * 4 + 0], inv, bv.x);
            float r1 = fmaf(a[c4 * 4 + 1], inv, bv.y);
            float r2 = fmaf(a[c4 * 4 + 2], inv, bv.z);
            float r3 = fmaf(a[c4 * 4 + 3], inv, bv.w);
            r0 = r0 > 0.f ? r0 : __expf(r0) - 1.f;
            r1 = r1 > 0.f ? r1 : __expf(r1) - 1.f;
            r2 = r2 > 0.f ? r2 : __expf(r2) - 1.f;
            r3 = r3 > 0.f ? r3 : __expf(r3) - 1.f;
            *(float4*)&ob[c4 * 4] = make_float4(r0, r1, r2, r3);
        }
    }
}

// ---------------- launch ----------------
extern "C" void kernel_launch(void* const* d_in, const int* in_sizes, int n_in,
                              void* d_out, int out_size, void* d_ws, size_t ws_size,
                              hipStream_t stream) {
    const float* x     = (const float*)d_in[0];
    const int*   ei    = (const int*)d_in[1];     // int32 [2][E] flat
    const float* W     = (const float*)d_in[2];
    const float* att_s = (const float*)d_in[3];
    const float* att_d = (const float*)d_in[4];
    const float* bias  = (const float*)d_in[5];
    float* out = (float*)d_out;

    int N = in_sizes[0] / 128;
    int E = in_sizes[1] / 2;
    int total = E + N;

    int nps = (N + NB - 1) / NB;                  // 391 (<512 for 9-bit pack)
    float inv_nps = 1.0f / (float)nps;
    int chunk = (total + NBLK - 1) / NBLK;        // ~6642 (<= OSCAP)

    auto align256 = [](size_t v) { return (v + 255) & ~(size_t)255; };
    char* wsp = (char*)d_ws;
    size_t off = 0;
    auto alloc = [&](size_t bytes) {
        char* p = wsp + off;
        off += align256(bytes);
        return p;
    };
    unsigned short* h  = (unsigned short*)alloc((size_t)N * 128 * 2);
    float* as        = (float*)alloc((size_t)N * 16);
    float* ad        = (float*)alloc((size_t)N * 16);
    int*   cntT      = (int*)alloc((size_t)NB * NBLK * 4);
    int*   fragRow   = (int*)alloc((size_t)NBLK * NB * 4);
    unsigned* pairs  = (unsigned*)alloc((size_t)NBLK * chunk * 4);
    int*   csrc      = (int*)alloc((size_t)total * 4);
    int*   rowptr    = (int*)alloc((size_t)(N + 1) * 4);
    (void)ws_size;

    int nGemm = (N + 127) / 128;                  // 782
    int nAtt  = ((size_t)N * 64 + 255) / 256;     // 25000

    k_gemm_sortA<<<NBLK + nGemm, 256, 0, stream>>>(x, W, h, N, ei, E, N, nps, inv_nps,
                                                   cntT, fragRow, pairs, chunk);
    k_binB_att<<<NB + nAtt, 256, 0, stream>>>(pairs, cntT, fragRow, csrc, rowptr,
                                              h, att_s, att_d, as, ad, N, nps, chunk);
    k_agg<<<(N + 3) / 4, 256, 0, stream>>>(h, rowptr, csrc, as, ad, bias, out, N);
}